// Round 1
// 260.417 us; speedup vs baseline: 1.2205x; 1.2205x over previous
//
#include <hip/hip_runtime.h>
#include <hip/hip_bf16.h>
#include <math.h>

// Problem constants
#define NB   4096      // graphs
#define MM   64        // points per graph
#define KNN  3
#define FX   59
#define H    128
#define NN   (NB*MM)       // 262144 nodes
#define NE   (NN*KNN)      // 786432 edges
#define C1   256
#define EPSB 1e-5f

typedef __attribute__((ext_vector_type(8))) short short8;   // 8 bf16 (4 VGPRs)
typedef __attribute__((ext_vector_type(4))) float f32x4;

__device__ __forceinline__ float wave_red(float v) {
#pragma unroll
    for (int m = 32; m >= 1; m >>= 1) v += __shfl_xor(v, m, 64);
    return v;
}

__device__ __forceinline__ unsigned short f2bf(float f) {
    union { float f; unsigned u; } v; v.f = f;
    unsigned r = v.u + 0x7fffu + ((v.u >> 16) & 1u);   // round-to-nearest-even
    return (unsigned short)(r >> 16);
}

// pack two f32 -> u32 of 2 bf16 (lo = a, hi = b), RNE
__device__ __forceinline__ unsigned int pack_bf2(float a, float b) {
    union { __hip_bfloat162 h; unsigned int u; } cv;
    cv.h = __float22bfloat162_rn(make_float2(a, b));
    return cv.u;
}

// ---------------------------------------------------------------------------
// prep1: W1t[n][k] = bf16(W1[k][n]), k padded 62->64 with zeros. grid=128,blk=64
// ---------------------------------------------------------------------------
__global__ __launch_bounds__(64) void k_prep1(
    const float* __restrict__ W1, unsigned short* __restrict__ W1t)
{
    const int n = blockIdx.x, k = threadIdx.x;
    W1t[n * 64 + k] = (k < 62) ? f2bf(W1[k * H + n]) : (unsigned short)0;
}

// ---------------------------------------------------------------------------
// prep2 (after BN1 stats): W2t[n][k] = bf16(a1[k]*W2[k][n]);
// b2p[n] = b2[n] + sum_k c1[k]*W2[k][n].  grid=128, blk=128
// ---------------------------------------------------------------------------
__global__ __launch_bounds__(128) void k_prep2(
    const float* __restrict__ W2, const float* __restrict__ affine1,
    const float* __restrict__ b2, unsigned short* __restrict__ W2t,
    float* __restrict__ b2p)
{
    const int n = blockIdx.x, k = threadIdx.x;
    float wv = W2[k * H + n];
    W2t[n * H + k] = f2bf(affine1[k] * wv);
    float contrib = wave_red(affine1[H + k] * wv);
    __shared__ float red2[2];
    if ((k & 63) == 0) red2[k >> 6] = contrib;
    __syncthreads();
    if (k == 0) b2p[n] = b2[n] + red2[0] + red2[1];
}

// ---------------------------------------------------------------------------
// K1 (fused prepx + kNN + MFMA1 + combine):
//   stage bf16([x|pos|0,0]) -> a_s; parallel kNN (4 thr/node, shfl merge);
//   u^T = W1t @ a_s^T via swapped-operand MFMA -> channel-pair-packed u_s32;
//   combine: wave = all 128 ch of one node/iter (lane owns ch pair), b32 LDS
//   reads, coalesced u32 h1max stores; in-block BN1 partial reduce.
// grid = 4096, 256 threads. LDS 29.7 KB -> 5 blocks/CU.
// ---------------------------------------------------------------------------
__global__ __launch_bounds__(256) void k_knn_mfma1(
    const float* __restrict__ x, const float* __restrict__ pos,
    const unsigned short* __restrict__ W1t, const float* __restrict__ W1,
    const float* __restrict__ b1,
    unsigned short* __restrict__ h1max, float* __restrict__ p1s,
    float* __restrict__ p1q)
{
    __shared__ float pos_s[MM * 3];
    __shared__ int   nbr_s[MM * 3];
    __shared__ float b1_s[H];
    __shared__ float w1p_s[3 * H];
    __shared__ __align__(16) unsigned short a_s[MM * 72];    // 64x64 bf16, stride 72
    __shared__ __align__(16) unsigned int   u_s32[MM * 66];  // 64 x 66 u32 (= 132 bf16/row)

    const int blk = blockIdx.x, tid = threadIdx.x;
    const float* xg = x + (size_t)blk * MM * FX;
    const float* pg = pos + (size_t)blk * MM * 3;

    // --- fused prepx: thread = quarter node row (16 cols), f32 -> bf16 -> a_s
    {
        const int node = tid >> 2, c0g = (tid & 3) * 16;
        unsigned short vals[16];
#pragma unroll
        for (int i = 0; i < 16; ++i) {
            int c = c0g + i;
            float v = (c < FX) ? xg[node * FX + c]
                               : ((c < 62) ? pg[node * 3 + (c - FX)] : 0.f);
            vals[i] = f2bf(v);
        }
        *(short8*)(a_s + node * 72 + c0g)     = *(short8*)&vals[0];
        *(short8*)(a_s + node * 72 + c0g + 8) = *(short8*)&vals[8];
    }
    for (int t = tid; t < MM * 3; t += 256) pos_s[t] = pg[t];
    if (tid < H) b1_s[tid] = b1[tid];
    for (int t = tid; t < 3 * H; t += 256) w1p_s[t] = W1[(FX + (t >> 7)) * H + (t & 127)];
    __syncthreads();

    // --- parallel kNN: 4 threads per node, each scans 16 candidates; merge
    //     via shfl_xor(1), shfl_xor(2). Lexicographic (d, idx) == top_k ties.
    {
        const int node = tid >> 2, q = tid & 3;
        const float px = pos_s[node * 3 + 0];
        const float py = pos_s[node * 3 + 1];
        const float pz = pos_s[node * 3 + 2];
        float d0 = 1e30f, d1 = 1e30f, d2 = 1e30f;
        int   i0 = 1 << 30, i1 = 1 << 30, i2 = 1 << 30;
        for (int jj = 0; jj < 16; ++jj) {
            int j = q * 16 + jj;
            if (j == node) continue;
            float dx = pos_s[j * 3 + 0] - px;
            float dy = pos_s[j * 3 + 1] - py;
            float dz = pos_s[j * 3 + 2] - pz;
            float d = dx * dx + dy * dy + dz * dz;
            bool b2v = (d < d2) || (d == d2 && j < i2);
            bool b1v = (d < d1) || (d == d1 && j < i1);
            bool b0v = (d < d0) || (d == d0 && j < i0);
            float nd2 = b1v ? d1 : d; int ni2 = b1v ? i1 : j;
            float nd1 = b0v ? d0 : d; int ni1 = b0v ? i0 : j;
            d2 = b2v ? nd2 : d2; i2 = b2v ? ni2 : i2;
            d1 = b1v ? nd1 : d1; i1 = b1v ? ni1 : i1;
            d0 = b0v ? d   : d0; i0 = b0v ? j   : i0;
        }
#pragma unroll
        for (int mq = 1; mq <= 2; mq <<= 1) {
            float e[3]; int f[3];
            e[0] = __shfl_xor(d0, mq, 64); f[0] = __shfl_xor(i0, mq, 64);
            e[1] = __shfl_xor(d1, mq, 64); f[1] = __shfl_xor(i1, mq, 64);
            e[2] = __shfl_xor(d2, mq, 64); f[2] = __shfl_xor(i2, mq, 64);
#pragma unroll
            for (int t3 = 0; t3 < 3; ++t3) {
                float ev = e[t3]; int fv = f[t3];
                bool b2v = (ev < d2) || (ev == d2 && fv < i2);
                bool b1v = (ev < d1) || (ev == d1 && fv < i1);
                bool b0v = (ev < d0) || (ev == d0 && fv < i0);
                float nd2 = b1v ? d1 : ev; int ni2 = b1v ? i1 : fv;
                float nd1 = b0v ? d0 : ev; int ni1 = b0v ? i0 : fv;
                d2 = b2v ? nd2 : d2; i2 = b2v ? ni2 : i2;
                d1 = b1v ? nd1 : d1; i1 = b1v ? ni1 : i1;
                d0 = b0v ? ev  : d0; i0 = b0v ? fv  : i0;
            }
        }
        if (q == 0) {
            nbr_s[node * 3 + 0] = i0;
            nbr_s[node * 3 + 1] = i1;
            nbr_s[node * 3 + 2] = i2;
        }
    }

    // --- MFMA (swapped operands): D tile = [16 ch][16 node].
    // wave w owns channels [w*32, w*32+32), all 64 nodes.
    const int lane = tid & 63;
    const int w    = tid >> 6;
    const int wcol = w * 32;
    const int m    = lane & 15;
    const int kg   = lane >> 4;

    short8 bfr[2][2];
#pragma unroll
    for (int ct = 0; ct < 2; ++ct)
#pragma unroll
        for (int kc = 0; kc < 2; ++kc)
            bfr[ct][kc] = *(const short8*)(W1t + (wcol + ct * 16 + m) * 64 + kc * 32 + kg * 8);

    f32x4 acc[4][2];
#pragma unroll
    for (int rt = 0; rt < 4; ++rt)
#pragma unroll
        for (int ct = 0; ct < 2; ++ct) acc[rt][ct] = (f32x4){0.f, 0.f, 0.f, 0.f};

#pragma unroll
    for (int kc = 0; kc < 2; ++kc)
#pragma unroll
        for (int rt = 0; rt < 4; ++rt) {
            short8 a = *(const short8*)(a_s + (rt * 16 + m) * 72 + kc * 32 + kg * 8);
#pragma unroll
            for (int ct = 0; ct < 2; ++ct)
                acc[rt][ct] = __builtin_amdgcn_mfma_f32_16x16x32_bf16(bfr[ct][kc], a, acc[rt][ct], 0, 0, 0);
        }
    // D layout: col(=node) = lane&15, row(=ch in tile) = kg*4 + reg  [m89/m91]
    // lane holds 4 consecutive channels of node (rt*16+m): pack -> 1 b64 write.
#pragma unroll
    for (int rt = 0; rt < 4; ++rt)
#pragma unroll
        for (int ct = 0; ct < 2; ++ct) {
            int node = rt * 16 + m;
            int pidx = 16 * w + 8 * ct + 2 * kg;   // u32 index = (channel base)/2
            uint2 val;
            val.x = pack_bf2(acc[rt][ct][0], acc[rt][ct][1]);
            val.y = pack_bf2(acc[rt][ct][2], acc[rt][ct][3]);
            *(uint2*)(u_s32 + node * 66 + pidx) = val;
        }
    __syncthreads();

    // --- combine: wave w handles nodes [w*16, w*16+16); lane owns channels
    //     (2*lane, 2*lane+1). nbr/pos reads are wave-uniform broadcasts.
    const int c0 = 2 * lane, c1v = 2 * lane + 1;
    const float wpa0 = w1p_s[c0],      wpa1 = w1p_s[H + c0],  wpa2 = w1p_s[2 * H + c0];
    const float wpb0 = w1p_s[c1v],     wpb1 = w1p_s[H + c1v], wpb2 = w1p_s[2 * H + c1v];
    const float b1a = b1_s[c0], b1b = b1_s[c1v];
    float s0 = 0.f, s1 = 0.f, q0 = 0.f, q1 = 0.f;
    unsigned int* hout32 = (unsigned int*)(h1max + (size_t)blk * MM * H);
    for (int ii = 0; ii < 16; ++ii) {
        int node = w * 16 + ii;
        int j0 = nbr_s[node * 3 + 0];
        int j1 = nbr_s[node * 3 + 1];
        int j2 = nbr_s[node * 3 + 2];
        float px = pos_s[node * 3 + 0], py = pos_s[node * 3 + 1], pz = pos_s[node * 3 + 2];
        float basea = b1a - (px * wpa0 + py * wpa1 + pz * wpa2);
        float baseb = b1b - (px * wpb0 + py * wpb1 + pz * wpb2);
        unsigned int v0 = u_s32[j0 * 66 + lane];
        unsigned int v1 = u_s32[j1 * 66 + lane];
        unsigned int v2 = u_s32[j2 * 66 + lane];
        float h0a = fmaxf(__uint_as_float(v0 << 16) + basea, 0.f);
        float h1a = fmaxf(__uint_as_float(v1 << 16) + basea, 0.f);
        float h2a = fmaxf(__uint_as_float(v2 << 16) + basea, 0.f);
        float h0b = fmaxf(__uint_as_float(v0 & 0xffff0000u) + baseb, 0.f);
        float h1b = fmaxf(__uint_as_float(v1 & 0xffff0000u) + baseb, 0.f);
        float h2b = fmaxf(__uint_as_float(v2 & 0xffff0000u) + baseb, 0.f);
        s0 += h0a + h1a + h2a; q0 += h0a * h0a + h1a * h1a + h2a * h2a;
        s1 += h0b + h1b + h2b; q1 += h0b * h0b + h1b * h1b + h2b * h2b;
        float ma = fmaxf(fmaxf(h0a, h1a), h2a);
        float mb = fmaxf(fmaxf(h0b, h1b), h2b);
        hout32[node * 64 + lane] = pack_bf2(ma, mb);
    }

    // --- in-block BN1 partial reduce (red buffer overlaid on dead a_s)
    float* red_s = (float*)a_s;   // 1024 floats = 4 KB <= 9216 B
    *(float2*)(red_s + w * 128 + c0)       = make_float2(s0, s1);
    *(float2*)(red_s + 512 + w * 128 + c0) = make_float2(q0, q1);
    __syncthreads();
    if (tid < 128) {
        float S = red_s[tid] + red_s[128 + tid] + red_s[256 + tid] + red_s[384 + tid];
        p1s[(size_t)blk * H + tid] = S;
    } else {
        int t2 = tid - 128;
        float Q = red_s[512 + t2] + red_s[640 + t2] + red_s[768 + t2] + red_s[896 + t2];
        p1q[(size_t)blk * H + t2] = Q;
    }
}

// ---------------------------------------------------------------------------
// k_stats: per-channel reduce of partials -> BN affine (a, c).
// Partials laid out [p][c] with row stride ld (coalesced producer writes).
// ---------------------------------------------------------------------------
__global__ __launch_bounds__(256) void k_stats(
    const float* __restrict__ ps, const float* __restrict__ pq, int P, int ld,
    float invCnt, const float* __restrict__ g, const float* __restrict__ be,
    float* __restrict__ affine, int C)
{
    const int c = blockIdx.x, tid = threadIdx.x;
    float s = 0.f, q = 0.f;
    for (int p = tid; p < P; p += 256) {
        s += ps[(size_t)p * ld + c];
        q += pq[(size_t)p * ld + c];
    }
    s = wave_red(s); q = wave_red(q);
    __shared__ float rs_s[4], rq_s[4];
    if ((tid & 63) == 0) { rs_s[tid >> 6] = s; rq_s[tid >> 6] = q; }
    __syncthreads();
    if (tid == 0) {
        float S = rs_s[0] + rs_s[1] + rs_s[2] + rs_s[3];
        float Q = rq_s[0] + rq_s[1] + rq_s[2] + rq_s[3];
        float mu  = S * invCnt;
        float var = Q * invCnt - mu * mu;
        float a   = g[c] * rsqrtf(var + EPSB);
        affine[c]     = a;
        affine[C + c] = be[c] - mu * a;
    }
}

// ---------------------------------------------------------------------------
// K3: h2 = relu(h1max(bf16) @ W2t + b2p) via MFMA; per-graph col sums + stats.
// grid = 4096, 256 threads; wave owns 32 cols over all 64 rows
// ---------------------------------------------------------------------------
__global__ __launch_bounds__(256) void k_mfma2(
    const unsigned short* __restrict__ h1max, const unsigned short* __restrict__ W2t,
    const float* __restrict__ b2p,
    float* __restrict__ graphsum, float* __restrict__ p2s, float* __restrict__ p2q)
{
    __shared__ __align__(16) unsigned short a_s[MM * 136];  // 64x128 bf16, stride 136
    const int blk = blockIdx.x, tid = threadIdx.x;
    const unsigned short* hg = h1max + (size_t)blk * MM * H;
    for (int t = tid; t < MM * H / 8; t += 256) {
        int row = t >> 4, col8 = (t & 15) * 8;
        *(short8*)(a_s + row * 136 + col8) = *(const short8*)(hg + row * H + col8);
    }
    __syncthreads();

    const int lane = tid & 63, w = tid >> 6, wcol = w * 32;
    const int m = lane & 15, kg = lane >> 4;

    short8 bfr[2][4];
#pragma unroll
    for (int ct = 0; ct < 2; ++ct)
#pragma unroll
        for (int kc = 0; kc < 4; ++kc)
            bfr[ct][kc] = *(const short8*)(W2t + (wcol + ct * 16 + m) * H + kc * 32 + kg * 8);

    f32x4 acc[4][2];
#pragma unroll
    for (int rt = 0; rt < 4; ++rt)
#pragma unroll
        for (int ct = 0; ct < 2; ++ct) acc[rt][ct] = (f32x4){0.f, 0.f, 0.f, 0.f};

#pragma unroll
    for (int kc = 0; kc < 4; ++kc)
#pragma unroll
        for (int rt = 0; rt < 4; ++rt) {
            short8 a = *(const short8*)(a_s + (rt * 16 + m) * 136 + kc * 32 + kg * 8);
#pragma unroll
            for (int ct = 0; ct < 2; ++ct)
                acc[rt][ct] = __builtin_amdgcn_mfma_f32_16x16x32_bf16(a, bfr[ct][kc], acc[rt][ct], 0, 0, 0);
        }

#pragma unroll
    for (int ct = 0; ct < 2; ++ct) {
        float bv = b2p[wcol + ct * 16 + m];
        float s = 0.f, q = 0.f;
#pragma unroll
        for (int rt = 0; rt < 4; ++rt)
#pragma unroll
            for (int r = 0; r < 4; ++r) {
                float v = fmaxf(acc[rt][ct][r] + bv, 0.f);
                s += v; q += v * v;
            }
        s += __shfl_xor(s, 16, 64); q += __shfl_xor(q, 16, 64);
        s += __shfl_xor(s, 32, 64); q += __shfl_xor(q, 32, 64);
        if (lane < 16) {
            int col = wcol + ct * 16 + lane;
            graphsum[(size_t)blk * H + col] = s;
            p2s[(size_t)blk * H + col] = s;   // [blk][col] — coalesced
            p2q[(size_t)blk * H + col] = q;
        }
    }
}

// ---------------------------------------------------------------------------
// K5a: pooled = BN2(graphsum/64); c1 = ReLU(pooled @ Wc1 + bc1); stats over B.
// ---------------------------------------------------------------------------
__global__ __launch_bounds__(256) void k_cls1(
    const float* __restrict__ graphsum, const float* __restrict__ affine2,
    const float* __restrict__ Wc1, const float* __restrict__ bc1,
    float* __restrict__ c1raw, float* __restrict__ p3s, float* __restrict__ p3q)
{
    __shared__ float pooled_s[16 * H];
    const int blk = blockIdx.x, tid = threadIdx.x;
    const int g0 = blk * 16;
    for (int t = tid; t < 16 * H; t += 256) {
        int f = t & 127;
        pooled_s[t] = affine2[f] * (graphsum[(size_t)g0 * H + t] * (1.f / 64.f)) + affine2[H + f];
    }
    __syncthreads();
    const int c = tid;
    float acc[16];
    const float bias = bc1[c];
#pragma unroll
    for (int gi = 0; gi < 16; ++gi) acc[gi] = bias;
    for (int f = 0; f < H; ++f) {
        float w = Wc1[f * C1 + c];
#pragma unroll
        for (int gi = 0; gi < 16; ++gi) acc[gi] += pooled_s[gi * H + f] * w;
    }
    float s = 0.f, q = 0.f;
#pragma unroll
    for (int gi = 0; gi < 16; ++gi) {
        float h = fmaxf(acc[gi], 0.f);
        c1raw[(size_t)(g0 + gi) * C1 + c] = h;
        s += h; q += h * h;
    }
    p3s[(size_t)blk * C1 + c] = s;   // [blk][c] — coalesced
    p3q[(size_t)blk * C1 + c] = q;
}

// ---------------------------------------------------------------------------
// K5c: z = ReLU(BN(c1) @ Wc2 + bc2) per graph; partial stats of z.
// ---------------------------------------------------------------------------
__global__ __launch_bounds__(256) void k_cls2(
    const float* __restrict__ c1raw, const float* __restrict__ affine3,
    const float* __restrict__ Wc2, const float* __restrict__ bc2,
    float* __restrict__ z, float* __restrict__ pz, float* __restrict__ pzq)
{
    __shared__ float a_s[C1], c_s[C1], w_s[C1];
    const int blk = blockIdx.x, tid = threadIdx.x;
    a_s[tid] = affine3[tid];
    c_s[tid] = affine3[C1 + tid];
    w_s[tid] = Wc2[tid];
    __syncthreads();
    const int g = blk * 256 + tid;
    float acc = bc2[0];
    for (int f = 0; f < C1; f += 4) {
        float4 cv = *(const float4*)&c1raw[(size_t)g * C1 + f];
        acc += (a_s[f + 0] * cv.x + c_s[f + 0]) * w_s[f + 0];
        acc += (a_s[f + 1] * cv.y + c_s[f + 1]) * w_s[f + 1];
        acc += (a_s[f + 2] * cv.z + c_s[f + 2]) * w_s[f + 2];
        acc += (a_s[f + 3] * cv.w + c_s[f + 3]) * w_s[f + 3];
    }
    float zz = fmaxf(acc, 0.f);
    z[g] = zz;
    float s = wave_red(zz);
    float q = wave_red(zz * zz);
    __shared__ float rs_s[4], rq_s[4];
    if ((tid & 63) == 0) { rs_s[tid >> 6] = s; rq_s[tid >> 6] = q; }
    __syncthreads();
    if (tid == 0) {
        pz[blk]  = rs_s[0] + rs_s[1] + rs_s[2] + rs_s[3];
        pzq[blk] = rq_s[0] + rq_s[1] + rq_s[2] + rq_s[3];
    }
}

// ---------------------------------------------------------------------------
// K5d: final BN over 4096 z + sigmoid -> out
// ---------------------------------------------------------------------------
__global__ __launch_bounds__(256) void k_final(
    const float* __restrict__ z, const float* __restrict__ pz,
    const float* __restrict__ pzq, const float* __restrict__ gc2,
    const float* __restrict__ bec2, float* __restrict__ out)
{
    __shared__ float ab[2];
    if (threadIdx.x == 0) {
        float S = 0.f, Q = 0.f;
        for (int p = 0; p < 16; ++p) { S += pz[p]; Q += pzq[p]; }
        float mu  = S * (1.f / 4096.f);
        float var = Q * (1.f / 4096.f) - mu * mu;
        float a   = gc2[0] * rsqrtf(var + EPSB);
        ab[0] = a;
        ab[1] = bec2[0] - mu * a;
    }
    __syncthreads();
    float a = ab[0], cb = ab[1];
    for (int g = threadIdx.x; g < NB; g += 256) {
        float v = a * z[g] + cb;
        out[g] = 1.f / (1.f + expf(-v));
    }
}

extern "C" void kernel_launch(void* const* d_in, const int* in_sizes, int n_in,
                              void* d_out, int out_size, void* d_ws, size_t ws_size,
                              hipStream_t stream)
{
    const float* x    = (const float*)d_in[0];
    const float* pos  = (const float*)d_in[1];
    // d_in[2] = batch (int32) — graphs are contiguous 64-node chunks; unused
    const float* W1   = (const float*)d_in[3];
    const float* b1   = (const float*)d_in[4];
    const float* g1   = (const float*)d_in[5];
    const float* be1  = (const float*)d_in[6];
    const float* W2   = (const float*)d_in[7];
    const float* b2   = (const float*)d_in[8];
    const float* g2   = (const float*)d_in[9];
    const float* be2  = (const float*)d_in[10];
    const float* Wc1  = (const float*)d_in[11];
    const float* bc1  = (const float*)d_in[12];
    const float* gc1  = (const float*)d_in[13];
    const float* bec1 = (const float*)d_in[14];
    const float* Wc2  = (const float*)d_in[15];
    const float* bc2  = (const float*)d_in[16];
    const float* gc2  = (const float*)d_in[17];
    const float* bec2 = (const float*)d_in[18];
    float* out = (float*)d_out;

    float* ws = (float*)d_ws;
    size_t off = 0;
    auto alloc = [&](size_t n) { float* p = ws + off; off += n; return p; };
    unsigned short* h1max = (unsigned short*)alloc((size_t)NN * H / 2);  // bf16, 67 MB
    unsigned short* W1t   = (unsigned short*)alloc(128 * 64 / 2);
    unsigned short* W2t   = (unsigned short*)alloc(128 * 128 / 2);
    float* b2p     = alloc(H);
    float* p1s     = alloc((size_t)NB * H);
    float* p1q     = alloc((size_t)NB * H);
    float* affine1 = alloc(2 * H);
    float* graphsum= alloc((size_t)NB * H);
    float* p2s     = alloc((size_t)NB * H);
    float* p2q     = alloc((size_t)NB * H);
    float* affine2 = alloc(2 * H);
    float* c1raw   = alloc((size_t)NB * C1);
    float* p3s     = alloc((size_t)256 * C1);
    float* p3q     = alloc((size_t)256 * C1);
    float* affine3 = alloc(2 * C1);
    float* zbuf    = alloc(NB);
    float* pz      = alloc(16);
    float* pzq     = alloc(16);

    k_prep1<<<dim3(128), dim3(64), 0, stream>>>(W1, W1t);
    k_knn_mfma1<<<dim3(NB), dim3(256), 0, stream>>>(x, pos, W1t, W1, b1, h1max, p1s, p1q);
    k_stats<<<dim3(H), dim3(256), 0, stream>>>(p1s, p1q, NB, H, 1.f / (float)NE, g1, be1, affine1, H);
    k_prep2<<<dim3(128), dim3(128), 0, stream>>>(W2, affine1, b2, W2t, b2p);
    k_mfma2<<<dim3(NB), dim3(256), 0, stream>>>(h1max, W2t, b2p, graphsum, p2s, p2q);
    k_stats<<<dim3(H), dim3(256), 0, stream>>>(p2s, p2q, NB, H, 1.f / (float)NN, g2, be2, affine2, H);
    k_cls1<<<dim3(256), dim3(256), 0, stream>>>(graphsum, affine2, Wc1, bc1, c1raw, p3s, p3q);
    k_stats<<<dim3(C1), dim3(256), 0, stream>>>(p3s, p3q, 256, C1, 1.f / (float)NB, gc1, bec1, affine3, C1);
    k_cls2<<<dim3(16), dim3(256), 0, stream>>>(c1raw, affine3, Wc2, bc2, zbuf, pz, pzq);
    k_final<<<dim3(1), dim3(256), 0, stream>>>(zbuf, pz, pzq, gc2, bec2, out);
}